// Round 9
// baseline (242.036 us; speedup 1.0000x reference)
//
#include <hip/hip_runtime.h>

// GRU B=32,T=50,N=1024,C=128,H=64 via fp16 MFMA 16x16x32, fp32 accum.
// R9: block = 16 seqs, 4 waves; wave jt owns hidden cols jt*16..+15.
// ALL weights in registers (Wih quarter 48 VGPR + Whh quarter 24 VGPR)
// -> zero weight-LDS traffic. x staged via global_load_lds (contiguous 1KB
// per instr, source granule-XOR pre-swizzled), 4-buffer rotation, counted
// s_waitcnt vmcnt(4) + raw s_barrier (never a full drain), depth-3 pipeline,
// ONE barrier per step. h via double-buffered swizzled LDS tile.
// launch_bounds(256,3): 12 waves/CU = 3 waves/SIMD.

typedef _Float16 half8 __attribute__((ext_vector_type(8)));
typedef float f32x4 __attribute__((ext_vector_type(4)));

constexpr int T_ = 50, N_ = 1024, C_ = 128, H_ = 64;
constexpr uint32_t XB_OFF = 0;        // 4 bufs x 8192 B (16 seq x 512B fp32)
constexpr uint32_t HB_OFF = 32768;    // 2 bufs x 2048 B (16 seq x 128B fp16)
constexpr int LDS_BYTES = 36864;

__global__ void prep_weights(const float* __restrict__ Wih, const float* __restrict__ Whh,
                             _Float16* __restrict__ w16) {
  int i = blockIdx.x * 256 + threadIdx.x;
  if (i < 192 * 128) w16[i] = (_Float16)Wih[i];
  if (i < 192 * 64)  w16[24576 + i] = (_Float16)Whh[i];
}

__device__ __forceinline__ float sigm(float x) {
  return __builtin_amdgcn_rcpf(1.f + __expf(-x));
}

__device__ __forceinline__ half8 cvt8(float4 lo, float4 hi) {
  half8 v;
  v[0] = (_Float16)lo.x; v[1] = (_Float16)lo.y;
  v[2] = (_Float16)lo.z; v[3] = (_Float16)lo.w;
  v[4] = (_Float16)hi.x; v[5] = (_Float16)hi.y;
  v[6] = (_Float16)hi.z; v[7] = (_Float16)hi.w;
  return v;
}

__device__ __forceinline__ void glds16(const char* g, char* l) {
  __builtin_amdgcn_global_load_lds(
      (const __attribute__((address_space(1))) void*)g,
      (__attribute__((address_space(3))) void*)l, 16, 0, 0);
}

__global__ __launch_bounds__(256, 3) void gru_glds(
    const float* __restrict__ x, const _Float16* __restrict__ w16,
    const float* __restrict__ bih, const float* __restrict__ bhh,
    float* __restrict__ out)
{
  __shared__ __align__(16) char lds[LDS_BYTES];
  const int tid = threadIdx.x;
  const int wv = tid >> 6, lane = tid & 63;
  const int c = lane & 15, g = lane >> 4;
  const int jt = wv;
  const int seq0 = blockIdx.x * 16;
  const int b = seq0 >> 10, n0 = seq0 & (N_ - 1);

  // zero h buf 1 (read at t=0): 2048 B, 8 B per thread
  *(uint2*)(lds + HB_OFF + 2048 + tid * 8) = (uint2){0u, 0u};

  // ---- weights fully in registers (loaded from fp16 workspace) ----
  half8 wr[3][4];   // Wih quarter: row = gate*64 + jt*16 + c, k = ks*32 + g*8
#pragma unroll
  for (int gate = 0; gate < 3; ++gate)
#pragma unroll
    for (int ks = 0; ks < 4; ++ks)
      wr[gate][ks] = *(const half8*)(w16 + (gate * 64 + jt * 16 + c) * 128 + ks * 32 + g * 8);
  half8 wf[3][2];   // Whh quarter: row = gate*64 + jt*16 + c, k = ks2*32 + g*8
  const _Float16* whh = w16 + 24576;
#pragma unroll
  for (int gate = 0; gate < 3; ++gate)
#pragma unroll
    for (int ks2 = 0; ks2 < 2; ++ks2)
      wf[gate][ks2] = *(const half8*)(whh + (gate * 64 + jt * 16 + c) * 64 + ks2 * 32 + g * 8);

  const int j = jt * 16 + c;
  const float br   = bih[j] + bhh[j];
  const float bz   = bih[64 + j] + bhh[64 + j];
  const float bin_ = bih[128 + j];
  const float bhn_ = bhh[128 + j];

  float hr[4] = {0.f, 0.f, 0.f, 0.f};

  // ---- glds source offsets (granule-XOR pre-swizzle) ----
  // dest (linear): chunk ch = 2*wv+i, lds byte ch*1024 + lane*16
  //   -> (row s_d = 2ch + (lane>>5), lds-granule gl = lane&31)
  // source data granule: gd = (gl&24) | ((gl&7) ^ (s_d&7)); byte = s_d*512 + gd*16
  uint32_t sofs[2];
#pragma unroll
  for (int i = 0; i < 2; ++i) {
    const int s_d = 4 * wv + 2 * i + (lane >> 5);
    const uint32_t gd = (uint32_t)((lane & 24) | ((lane & 7) ^ (s_d & 7)));
    sofs[i] = (uint32_t)s_d * 512 + gd * 16;
  }
  const size_t tilestride = (size_t)N_ * C_ * 4;   // bytes per t-step
  const char* tile0 = (const char*)(x + ((size_t)b * T_ * N_ + n0) * C_);

#define ISSUE_X(tt)                                                         \
  do {                                                                      \
    const int tcl = ((tt) < T_) ? (tt) : T_ - 1;                            \
    const char* tb = tile0 + (size_t)tcl * tilestride;                      \
    char* ldb = lds + XB_OFF + (uint32_t)((tt) & 3) * 8192 + (uint32_t)wv * 2048; \
    glds16(tb + sofs[0], ldb);                                              \
    glds16(tb + sofs[1], ldb + 1024);                                       \
  } while (0)

#define MFMA16(a, bf, acc) __builtin_amdgcn_mfma_f32_16x16x32_f16((a), (bf), (acc), 0, 0, 0)

  // ---- prologue: fill pipeline with gens 0,1,2 (6 glds outstanding) ----
  ISSUE_X(0); ISSUE_X(1); ISSUE_X(2);

  for (int t = 0; t < T_; ++t) {
    // gen t ready when <=4 newer vmem outstanding; h(t-1)+zero writes drained
    asm volatile("s_waitcnt vmcnt(4) lgkmcnt(0)" ::: "memory");
    __builtin_amdgcn_s_barrier();
    __builtin_amdgcn_sched_barrier(0);

    ISSUE_X(t + 3);   // into buf (t-1)&3, whose reads finished last step

    // h A-frags (fp16, swizzled): row c, granule (ks2*4+g) ^ (c&7)
    const uint32_t hrb = HB_OFF + (uint32_t)((t + 1) & 1) * 2048;
    half8 ha[2];
#pragma unroll
    for (int ks2 = 0; ks2 < 2; ++ks2)
      ha[ks2] = *(const half8*)(lds + hrb + (uint32_t)c * 128 +
                                (uint32_t)(((ks2 * 4 + g) ^ (c & 7)) << 4));

    f32x4 aR = {0.f, 0.f, 0.f, 0.f}, aZ = {0.f, 0.f, 0.f, 0.f};
    f32x4 aN = {0.f, 0.f, 0.f, 0.f}, aH = {0.f, 0.f, 0.f, 0.f};

    // gi: K=128; x A-frags from swizzled fp32 tile, cvt to fp16 on the fly
    const uint32_t xrb = XB_OFF + (uint32_t)(t & 3) * 8192 + (uint32_t)c * 512;
#pragma unroll
    for (int ks = 0; ks < 4; ++ks) {
      const float4 p0 = *(const float4*)(lds + xrb +
                          (uint32_t)((ks * 8 + ((g * 2 + 0) ^ (c & 7))) << 4));
      const float4 p1 = *(const float4*)(lds + xrb +
                          (uint32_t)((ks * 8 + ((g * 2 + 1) ^ (c & 7))) << 4));
      const half8 a = cvt8(p0, p1);
      aR = MFMA16(a, wr[0][ks], aR);
      aZ = MFMA16(a, wr[1][ks], aZ);
      aN = MFMA16(a, wr[2][ks], aN);
    }
    // gh: K=64; Whh from registers
#pragma unroll
    for (int ks2 = 0; ks2 < 2; ++ks2) {
      aR = MFMA16(ha[ks2], wf[0][ks2], aR);
      aZ = MFMA16(ha[ks2], wf[1][ks2], aZ);
      aH = MFMA16(ha[ks2], wf[2][ks2], aH);
    }

    // gates: lane holds D(seq = g*4+v, col j); write h(t) into buf t&1
    const uint32_t hwb = HB_OFF + (uint32_t)(t & 1) * 2048;
#pragma unroll
    for (int v = 0; v < 4; ++v) {
      const float r = sigm(aR[v] + br);
      const float z = sigm(aZ[v] + bz);
      const float np = aN[v] + bin_ + r * (aH[v] + bhn_);
      const float nn = 1.f - 2.f * __builtin_amdgcn_rcpf(__expf(2.f * np) + 1.f);
      const float hn = (1.f - z) * nn + z * hr[v];
      hr[v] = hn;
      const int seq = g * 4 + v;
      const uint32_t gl = (uint32_t)((jt * 2 + (c >> 3)) ^ (seq & 7));
      *(_Float16*)(lds + hwb + (uint32_t)seq * 128 + (gl << 4) +
                   (uint32_t)((c & 7) * 2)) = (_Float16)hn;
    }
  }

  // ---- store final h (fp32 carry) ----
#pragma unroll
  for (int v = 0; v < 4; ++v)
    out[(size_t)(seq0 + g * 4 + v) * H_ + j] = hr[v];
#undef ISSUE_X
#undef MFMA16
}

extern "C" void kernel_launch(void* const* d_in, const int* in_sizes, int n_in,
                              void* d_out, int out_size, void* d_ws, size_t ws_size,
                              hipStream_t stream) {
  const float* chars = (const float*)d_in[0];
  const float* Wih   = (const float*)d_in[1];
  const float* Whh   = (const float*)d_in[2];
  const float* bih   = (const float*)d_in[3];
  const float* bhh   = (const float*)d_in[4];

  _Float16* w16 = (_Float16*)d_ws;   // 36864 f16 = 73728 B

  prep_weights<<<96, 256, 0, stream>>>(Wih, Whh, w16);
  gru_glds<<<2048, 256, 0, stream>>>(chars, w16, bih, bhh, (float*)d_out);
}

// Round 10
// 202.783 us; speedup vs baseline: 1.1936x; 1.1936x over previous
//
#include <hip/hip_runtime.h>

// GRU B=32,T=50,N=1024,C=128,H=64 via fp16 MFMA 16x16x32, fp32 accum.
// R10 = R7 (2048 blocks x 4 waves, block owns 16 seqs, wave jt owns 16 hidden
// cols, Wih quarter in regs, Whh in LDS, x staged to LDS f16 dbuf, 128 VGPR,
// 4 blocks/CU -> 4 waves/SIMD) with the BARRIER DRAIN FIXED:
//   __syncthreads (drains vmcnt -> kills the x(t+2) prefetch every step)
//   -> s_waitcnt lgkmcnt(0) + raw s_barrier (global loads stay in flight).
// Plus s_setprio(1) around the MFMA cluster (T5; blocks are phase-staggered).

typedef _Float16 half8 __attribute__((ext_vector_type(8)));
typedef float f32x4 __attribute__((ext_vector_type(4)));

constexpr int T_ = 50, N_ = 1024, C_ = 128, H_ = 64;
constexpr uint32_t WHH_OFF = 0;       // 192 rows x 128B = 24576
constexpr uint32_t XB_OFF  = 24576;   // 2 x 4096 (16 seq x 128 f16) = 8192
constexpr uint32_t HB_OFF  = 32768;   // 2 x 2048 (16 seq x 64 f16)  = 4096
constexpr int LDS_BYTES = 36864;      // x4 blocks/CU = 147456 <= 163840

__global__ void prep_weights(const float* __restrict__ Wih, const float* __restrict__ Whh,
                             _Float16* __restrict__ w16) {
  int i = blockIdx.x * 256 + threadIdx.x;
  if (i < 192 * 128) w16[i] = (_Float16)Wih[i];
  if (i < 192 * 64)  w16[24576 + i] = (_Float16)Whh[i];
}

__device__ __forceinline__ float sigm(float x) {
  return __builtin_amdgcn_rcpf(1.f + __expf(-x));
}

__device__ __forceinline__ half8 cvt8(float4 lo, float4 hi) {
  half8 v;
  v[0] = (_Float16)lo.x; v[1] = (_Float16)lo.y;
  v[2] = (_Float16)lo.z; v[3] = (_Float16)lo.w;
  v[4] = (_Float16)hi.x; v[5] = (_Float16)hi.y;
  v[6] = (_Float16)hi.z; v[7] = (_Float16)hi.w;
  return v;
}

__global__ __launch_bounds__(256, 4) void gru_rb(
    const float* __restrict__ x, const _Float16* __restrict__ w16,
    const float* __restrict__ bih, const float* __restrict__ bhh,
    float* __restrict__ out)
{
  __shared__ __align__(16) char lds[LDS_BYTES];
  const int tid = threadIdx.x;
  const int wv = tid >> 6, lane = tid & 63;
  const int c = lane & 15, g = lane >> 4;
  const int jt = wv;                               // this wave's col tile
  const int seq0 = blockIdx.x * 16;
  const int b = seq0 >> 10, n0 = seq0 & (N_ - 1);

  // ---- stage Whh into LDS (128B rows, granule ^= row&7); zero h bufs ----
  {
    const _Float16* whh = w16 + 24576;
#pragma unroll
    for (int rep = 0; rep < 6; ++rep) {            // 1536 16B chunks
      int i = tid + rep * 256;
      int row = i >> 3, gr = i & 7;
      uint32_t byte = (uint32_t)row * 128 + (uint32_t)((gr ^ (row & 7)) << 4);
      *(half8*)(lds + WHH_OFF + byte) = *(const half8*)(whh + i * 8);
    }
    half8 zz = {};
    *(half8*)(lds + HB_OFF + tid * 16) = zz;       // 4096 B both h bufs
  }

  // ---- Wih quarter in registers: wr[gate][ks], row = gate*64 + jt*16 + c ----
  half8 wr[3][4];
#pragma unroll
  for (int gate = 0; gate < 3; ++gate)
#pragma unroll
    for (int ks = 0; ks < 4; ++ks)
      wr[gate][ks] = *(const half8*)(w16 + (gate * 64 + jt * 16 + c) * 128 + ks * 32 + g * 8);

  // ---- per-lane biases for hidden col j = jt*16 + c ----
  const int j = jt * 16 + c;
  const float br   = bih[j] + bhh[j];
  const float bz   = bih[64 + j] + bhh[64 + j];
  const float bin_ = bih[128 + j];
  const float bhn_ = bhh[128 + j];

  float hr[4] = {0.f, 0.f, 0.f, 0.f};             // h carry for seq = g*4+v

  // ---- x staging mapping: thread -> (seq = tid>>4, ch0 = (tid&15)*8) ----
  const int sseq = tid >> 4;
  const uint32_t xw_off = (uint32_t)sseq * 256 +
                          (uint32_t)(((tid & 15) ^ (sseq & 7)) << 4);
  const float* xbase = x + ((size_t)b * T_ * N_ + n0 + sseq) * C_ + (tid & 15) * 8;
  const size_t stepstride = (size_t)N_ * C_;

#define WHHB(gate, ks2) \
  (*(const half8*)(lds + WHH_OFF + (uint32_t)(((gate) * 64 + jt * 16 + c) * 128) + \
                   (uint32_t)((((ks2) * 4 + g) ^ (c & 7)) << 4)))
#define MFMA16(a, bf, acc) __builtin_amdgcn_mfma_f32_16x16x32_f16((a), (bf), (acc), 0, 0, 0)

  // ---- prologue: stage x(0) into xbuf[0]; issue raw loads for x(1) ----
  {
    float4 r0 = *(const float4*)(xbase);
    float4 r1 = *(const float4*)(xbase + 4);
    *(half8*)(lds + XB_OFF + xw_off) = cvt8(r0, r1);
  }
  float4 ra = *(const float4*)(xbase + stepstride);
  float4 rb = *(const float4*)(xbase + stepstride + 4);
  __syncthreads();   // prologue only

  for (int t = 0; t < T_; ++t) {
    const uint32_t xr  = XB_OFF + (uint32_t)(t & 1) * 4096;
    const uint32_t hrd = HB_OFF + (uint32_t)((t + 1) & 1) * 2048;
    const uint32_t hwr = HB_OFF + (uint32_t)(t & 1) * 2048;

    // A-frags from LDS: x row = c (16 granules), h row = c (8 granules)
    half8 xa[4];
#pragma unroll
    for (int ks = 0; ks < 4; ++ks)
      xa[ks] = *(const half8*)(lds + xr + (uint32_t)c * 256 +
                               (uint32_t)(((ks * 4 + g) ^ (c & 7)) << 4));
    half8 ha[2];
#pragma unroll
    for (int ks2 = 0; ks2 < 2; ++ks2)
      ha[ks2] = *(const half8*)(lds + hrd + (uint32_t)c * 128 +
                                (uint32_t)(((ks2 * 4 + g) ^ (c & 7)) << 4));

    f32x4 aR = {0.f, 0.f, 0.f, 0.f}, aZ = {0.f, 0.f, 0.f, 0.f};
    f32x4 aN = {0.f, 0.f, 0.f, 0.f}, aH = {0.f, 0.f, 0.f, 0.f};

    __builtin_amdgcn_s_setprio(1);
    // gi part (K=128, Wih from registers)
#pragma unroll
    for (int ks = 0; ks < 4; ++ks) {
      aR = MFMA16(xa[ks], wr[0][ks], aR);
      aZ = MFMA16(xa[ks], wr[1][ks], aZ);
      aN = MFMA16(xa[ks], wr[2][ks], aN);
    }
    // gh part (K=64, Whh from LDS)
#pragma unroll
    for (int ks2 = 0; ks2 < 2; ++ks2) {
      aR = MFMA16(ha[ks2], WHHB(0, ks2), aR);
      aZ = MFMA16(ha[ks2], WHHB(1, ks2), aZ);
      aH = MFMA16(ha[ks2], WHHB(2, ks2), aH);
    }
    __builtin_amdgcn_s_setprio(0);

    // gates: lane holds D(seq = g*4+v, col j); write h(t) to hbuf[t&1]
#pragma unroll
    for (int v = 0; v < 4; ++v) {
      const float r = sigm(aR[v] + br);
      const float z = sigm(aZ[v] + bz);
      const float np = aN[v] + bin_ + r * (aH[v] + bhn_);
      const float nn = 1.f - 2.f * __builtin_amdgcn_rcpf(__expf(2.f * np) + 1.f);
      const float hn = (1.f - z) * nn + z * hr[v];
      hr[v] = hn;
      const int seq = g * 4 + v;
      const uint32_t gr = (uint32_t)((jt * 2 + (c >> 3)) ^ (seq & 7));
      *(_Float16*)(lds + hwr + (uint32_t)seq * 128 + (gr << 4) +
                   (uint32_t)((c & 7) * 2)) = (_Float16)hn;
    }

    // stage x(t+1) into xbuf[(t+1)&1]; issue raw loads for x(t+2)
    if (t + 1 < T_) {
      *(half8*)(lds + XB_OFF + (uint32_t)((t + 1) & 1) * 4096 + xw_off) = cvt8(ra, rb);
      const int tn2 = (t + 2 < T_) ? t + 2 : T_ - 1;
      const float* xp = xbase + (size_t)tn2 * stepstride;
      ra = *(const float4*)(xp);
      rb = *(const float4*)(xp + 4);
    }

    // publish LDS writes (h + x-stage) WITHOUT draining vmcnt:
    // raw loads for x(t+2) stay in flight across the barrier.
    asm volatile("s_waitcnt lgkmcnt(0)" ::: "memory");
    __builtin_amdgcn_s_barrier();
  }

  // ---- store final h (fp32 carry) ----
#pragma unroll
  for (int v = 0; v < 4; ++v)
    out[(size_t)(seq0 + g * 4 + v) * H_ + j] = hr[v];
#undef WHHB
#undef MFMA16
}

extern "C" void kernel_launch(void* const* d_in, const int* in_sizes, int n_in,
                              void* d_out, int out_size, void* d_ws, size_t ws_size,
                              hipStream_t stream) {
  const float* chars = (const float*)d_in[0];
  const float* Wih   = (const float*)d_in[1];
  const float* Whh   = (const float*)d_in[2];
  const float* bih   = (const float*)d_in[3];
  const float* bhh   = (const float*)d_in[4];

  _Float16* w16 = (_Float16*)d_ws;   // 36864 f16 = 73728 B

  prep_weights<<<96, 256, 0, stream>>>(Wih, Whh, w16);
  gru_rb<<<2048, 256, 0, stream>>>(chars, w16, bih, bhh, (float*)d_out);
}